// Round 1
// baseline (525.723 us; speedup 1.0000x reference)
//
#include <hip/hip_runtime.h>
#include <math.h>

#define N_NODES 156
#define NFEAT 256
#define NHID 128
#define BATCH 16384
#define TT 24
#define HLSTM 32
#define G4 128            // 4*HLSTM
#define ALPHA 0.2f

// ---------------- K1: GAT s1/s2 (h = emb@W only feeds two dot products) ----
// grid (156, 2), block 128
__global__ void k_gat_s(const float* __restrict__ emb,
                        const float* __restrict__ Wr, const float* __restrict__ ar,
                        const float* __restrict__ Wp, const float* __restrict__ ap,
                        float* __restrict__ s_buf /* [2][2][156] */) {
    int i = blockIdx.x;
    int gat = blockIdx.y;
    const float* W = gat ? Wp : Wr;
    const float* a = gat ? ap : ar;
    int j = threadIdx.x; // 0..127
    __shared__ float erow[NFEAT];
    __shared__ float red[128];
    for (int k = j; k < NFEAT; k += 128) erow[k] = emb[i*NFEAT + k];
    __syncthreads();
    float h = 0.f;
    for (int k = 0; k < NFEAT; ++k) h = fmaf(erow[k], W[k*NHID + j], h);
    float v1 = h * a[j];
    float v2 = h * a[NHID + j];
    red[j] = v1; __syncthreads();
    for (int s = 64; s > 0; s >>= 1) { if (j < s) red[j] += red[j+s]; __syncthreads(); }
    if (j == 0) s_buf[(gat*2+0)*N_NODES + i] = red[0];
    __syncthreads();
    red[j] = v2; __syncthreads();
    for (int s = 64; s > 0; s >>= 1) { if (j < s) red[j] += red[j+s]; __syncthreads(); }
    if (j == 0) s_buf[(gat*2+1)*N_NODES + i] = red[0];
}

// ---------------- K2: masked leaky-relu softmax rows -> attn ----------------
// grid (156, 2), block 256
__global__ void k_attn(const float* __restrict__ s_buf, const int* __restrict__ adj,
                       float* __restrict__ attn /* [2][156][156] */) {
    int i = blockIdx.x, gat = blockIdx.y;
    int j = threadIdx.x;
    __shared__ float red[256];
    float s1 = s_buf[(gat*2+0)*N_NODES + i];
    bool act = (j < N_NODES);
    float e = -INFINITY;
    if (act) {
        float s2 = s_buf[(gat*2+1)*N_NODES + j];
        float z = s1 + s2;
        z = (z > 0.f) ? z : ALPHA * z;
        if (adj[i*N_NODES + j] <= 0) z = -9e15f;
        e = z;
    }
    red[j] = e; __syncthreads();
    for (int s = 128; s > 0; s >>= 1) { if (j < s) red[j] = fmaxf(red[j], red[j+s]); __syncthreads(); }
    float m = red[0]; __syncthreads();
    float val = act ? __expf(e - m) : 0.f;
    red[j] = val; __syncthreads();
    for (int s = 128; s > 0; s >>= 1) { if (j < s) red[j] += red[j+s]; __syncthreads(); }
    float inv = 1.f / red[0];
    if (act) attn[(gat*N_NODES + i)*N_NODES + j] = val * inv;
}

// ---------------- K3: M = Wih @ attn, bias = bih + bhh ---------------------
// grid (128, 2), block 192
__global__ void k_buildM(const float* __restrict__ attn,
                         const float* __restrict__ Wih_r, const float* __restrict__ Wih_p,
                         const float* __restrict__ bih_r, const float* __restrict__ bhh_r,
                         const float* __restrict__ bih_p, const float* __restrict__ bhh_p,
                         float* __restrict__ M /* [2][128][156] */,
                         float* __restrict__ bias /* [2][128] */) {
    int g = blockIdx.x, gat = blockIdx.y;
    const float* Wih = gat ? Wih_p : Wih_r;
    const float* A = attn + gat*N_NODES*N_NODES;
    int j = threadIdx.x;
    if (j < N_NODES) {
        float acc = 0.f;
        for (int n = 0; n < N_NODES; ++n)
            acc = fmaf(Wih[g*N_NODES + n], A[n*N_NODES + j], acc);
        M[(gat*G4 + g)*N_NODES + j] = acc;
    }
    if (blockIdx.x == 0 && j < G4)
        bias[gat*G4 + j] = gat ? (bih_p[j] + bhh_p[j]) : (bih_r[j] + bhh_r[j]);
}

// ---------------- K4: gates_in = x_t @ M.T  (fp32 register-tiled GEMM) -----
// grid (BATCH/128, CS), block 256. tile 128 rows(b) x 128 cols(g), K=156.
#define BK 52
#define LDK 132   // k-major LDS row stride: 16B-aligned, stride%32==4
__global__ void __launch_bounds__(256, 2)
k_gates(const float* __restrict__ x, const float* __restrict__ Mbuf,
        float* __restrict__ gbuf, int t0, int CS) {
    int tl = blockIdx.y;
    int t = t0 + tl;
    const float* M = Mbuf + (t < 4 ? 0 : G4*N_NODES);
    int b0 = blockIdx.x * 128;
    int tid = threadIdx.x;
    int tx = tid & 15, ty = tid >> 4;
    __shared__ float Xs[BK*LDK];
    __shared__ float Ms[BK*LDK];
    float acc[8][8];
    #pragma unroll
    for (int i = 0; i < 8; i++)
        #pragma unroll
        for (int jj = 0; jj < 8; jj++) acc[i][jj] = 0.f;

    for (int k0 = 0; k0 < N_NODES; k0 += BK) {
        __syncthreads();
        for (int idx = tid; idx < 128*BK; idx += 256) {   // 26 iters exactly
            int r = idx / BK, kk = idx - r*BK;
            Xs[kk*LDK + r] = x[(size_t)(b0 + r)*(TT*N_NODES) + t*N_NODES + k0 + kk];
            Ms[kk*LDK + r] = M[r*N_NODES + k0 + kk];
        }
        __syncthreads();
        #pragma unroll 4
        for (int kk = 0; kk < BK; ++kk) {
            const float* xp = &Xs[kk*LDK + ty*8];
            const float* mp = &Ms[kk*LDK + tx*8];
            float a[8], bb[8];
            #pragma unroll
            for (int i = 0; i < 8; i++) a[i] = xp[i];
            #pragma unroll
            for (int jj = 0; jj < 8; jj++) bb[jj] = mp[jj];
            #pragma unroll
            for (int i = 0; i < 8; i++)
                #pragma unroll
                for (int jj = 0; jj < 8; jj++)
                    acc[i][jj] = fmaf(a[i], bb[jj], acc[i][jj]);
        }
    }
    #pragma unroll
    for (int i = 0; i < 8; i++) {
        int b = b0 + ty*8 + i;
        float4* dst = (float4*)&gbuf[((size_t)b*CS + tl)*G4 + tx*8];
        dst[0] = make_float4(acc[i][0], acc[i][1], acc[i][2], acc[i][3]);
        dst[1] = make_float4(acc[i][4], acc[i][5], acc[i][6], acc[i][7]);
    }
}

// ---------------- K5: LSTM chunk (+ fc epilogue on last chunk) -------------
// grid 256, block 256; each block owns 64 batch rows.
// shared pool (floats): Wt[32][128]=4096 | bias[128] | g_s[64][128]=8192 | h_s[32][68]=2176
#define HPAD 68
__global__ void __launch_bounds__(256, 1)
k_lstm(const float* __restrict__ gbuf,
       const float* __restrict__ Whh_r, const float* __restrict__ Whh_p,
       const float* __restrict__ bias2,
       float* __restrict__ h_ws, float* __restrict__ c_ws, float* __restrict__ hr_ws,
       const float* __restrict__ fcW, const float* __restrict__ fcb,
       float* __restrict__ out, int t0, int CS) {
    __shared__ float sm[14592];
    float* Wt     = sm;          // [32][128] Whh^T
    float* bias_s = sm + 4096;   // [128]
    float* g_s    = sm + 4224;   // [64][128]
    float* h_s    = sm + 12416;  // [32][HPAD]
    int tid = threadIdx.x;
    int b0 = blockIdx.x * 64;
    int tE = t0 + CS;
    int tx = tid & 15, ty = tid >> 4;
    int dd = tid & 31, bg = tid >> 5;

    const float* Whh = (t0 < 4) ? Whh_r : Whh_p;
    const float* bsrc = bias2 + ((t0 < 4) ? 0 : G4);
    for (int idx = tid; idx < G4*HLSTM; idx += 256) {
        int g = idx >> 5, d = idx & 31;
        Wt[d*G4 + g] = Whh[idx];
    }
    if (tid < G4) bias_s[tid] = bsrc[tid];

    float cr[8];
    if (t0 == 0 || t0 == 4) {
        #pragma unroll
        for (int u = 0; u < 8; u++) cr[u] = 0.f;
        for (int idx = tid; idx < HLSTM*HPAD; idx += 256) h_s[idx] = 0.f;
    } else {
        for (int idx = tid; idx < 64*HLSTM; idx += 256) {
            int b = idx >> 5, d = idx & 31;
            h_s[d*HPAD + b] = h_ws[(size_t)(b0 + b)*HLSTM + d];
        }
        #pragma unroll
        for (int u = 0; u < 8; u++)
            cr[u] = c_ws[(size_t)(b0 + bg + u*8)*HLSTM + dd];
    }

    for (int tl = 0; tl < CS; ++tl) {
        __syncthreads();
        // A: issue gate-tile loads early (write to LDS after GEMM)
        float st[32];
        #pragma unroll
        for (int u = 0; u < 32; ++u) {
            int idx = tid + u*256;
            st[u] = gbuf[((size_t)(b0 + (idx >> 7))*CS + tl)*G4 + (idx & 127)];
        }
        // B: rec = h_prev @ Whh^T  (64x128, K=32)
        float acc[4][8];
        #pragma unroll
        for (int i = 0; i < 4; i++)
            #pragma unroll
            for (int jj = 0; jj < 8; jj++) acc[i][jj] = 0.f;
        #pragma unroll 8
        for (int k = 0; k < HLSTM; k++) {
            float a0 = h_s[k*HPAD + ty*4 + 0];
            float a1 = h_s[k*HPAD + ty*4 + 1];
            float a2 = h_s[k*HPAD + ty*4 + 2];
            float a3 = h_s[k*HPAD + ty*4 + 3];
            const float* wp = &Wt[k*G4 + tx*8];
            #pragma unroll
            for (int jj = 0; jj < 8; jj++) {
                float w = wp[jj];
                acc[0][jj] = fmaf(a0, w, acc[0][jj]);
                acc[1][jj] = fmaf(a1, w, acc[1][jj]);
                acc[2][jj] = fmaf(a2, w, acc[2][jj]);
                acc[3][jj] = fmaf(a3, w, acc[3][jj]);
            }
        }
        #pragma unroll
        for (int u = 0; u < 32; ++u) g_s[tid + u*256] = st[u];
        __syncthreads();
        // C: total gate pre-activation
        #pragma unroll
        for (int i = 0; i < 4; i++) {
            int r = ty*4 + i;
            #pragma unroll
            for (int jj = 0; jj < 8; jj++) {
                int c = tx*8 + jj;
                g_s[r*G4 + c] = acc[i][jj] + g_s[r*G4 + c] + bias_s[c];
            }
        }
        __syncthreads();
        // D: pointwise LSTM cell update (c in registers, h to LDS)
        #pragma unroll
        for (int u = 0; u < 8; u++) {
            int b = bg + u*8;
            float gi = g_s[b*G4 + dd];
            float gf = g_s[b*G4 + dd + 32];
            float gg = g_s[b*G4 + dd + 64];
            float go = g_s[b*G4 + dd + 96];
            float si = 1.f/(1.f + __expf(-gi));
            float sf = 1.f/(1.f + __expf(-gf));
            float so = 1.f/(1.f + __expf(-go));
            float tg = 1.f - 2.f/(__expf(2.f*gg) + 1.f);
            float c = sf*cr[u] + si*tg;
            cr[u] = c;
            float th = 1.f - 2.f/(__expf(2.f*c) + 1.f);
            h_s[dd*HPAD + b] = so*th;
        }
    }
    __syncthreads();

    if (tE == 4) {                 // end of recent LSTM: stash h_r
        for (int idx = tid; idx < 64*HLSTM; idx += 256) {
            int b = idx >> 5, d = idx & 31;
            hr_ws[(size_t)(b0 + b)*HLSTM + d] = h_s[d*HPAD + b];
        }
    } else if (tE == TT) {         // final chunk: fused fc epilogue
        float* fcW_s = sm;           // [156][65]
        float* hr_s  = sm + 10140;   // [64][32]
        float* fcb_s = sm + 12188;   // [156]
        for (int idx = tid; idx < N_NODES*64; idx += 256) {
            int n = idx >> 6, d2 = idx & 63;
            fcW_s[n*65 + d2] = fcW[idx];
        }
        for (int idx = tid; idx < 64*HLSTM; idx += 256) {
            int b = idx >> 5, d = idx & 31;
            hr_s[b*HLSTM + d] = hr_ws[(size_t)(b0 + b)*HLSTM + d];
        }
        if (tid < N_NODES) fcb_s[tid] = fcb[tid];
        __syncthreads();
        for (int idx = tid; idx < 64*N_NODES; idx += 256) {   // 39 iters exactly
            int b = idx / N_NODES, n = idx - b*N_NODES;
            float accv = fcb_s[n];
            #pragma unroll 8
            for (int d = 0; d < HLSTM; ++d) {
                accv = fmaf(hr_s[b*HLSTM + d], fcW_s[n*65 + d], accv);
                accv = fmaf(h_s[d*HPAD + b],  fcW_s[n*65 + 32 + d], accv);
            }
            out[(size_t)(b0 + b)*N_NODES + n] = accv;
        }
    } else {                       // persist period-LSTM state
        for (int idx = tid; idx < 64*HLSTM; idx += 256) {
            int b = idx >> 5, d = idx & 31;
            h_ws[(size_t)(b0 + b)*HLSTM + d] = h_s[d*HPAD + b];
        }
        #pragma unroll
        for (int u = 0; u < 8; u++)
            c_ws[(size_t)(b0 + bg + u*8)*HLSTM + dd] = cr[u];
    }
}

extern "C" void kernel_launch(void* const* d_in, const int* in_sizes, int n_in,
                              void* d_out, int out_size, void* d_ws, size_t ws_size,
                              hipStream_t stream) {
    (void)in_sizes; (void)n_in; (void)out_size;
    const float* emb   = (const float*)d_in[0];
    const float* x     = (const float*)d_in[1];
    const int*   adj   = (const int*)d_in[2];
    const float* Wr    = (const float*)d_in[3];
    const float* ar    = (const float*)d_in[4];
    const float* Wp    = (const float*)d_in[5];
    const float* ap    = (const float*)d_in[6];
    const float* Wih_r = (const float*)d_in[7];
    const float* Whh_r = (const float*)d_in[8];
    const float* bih_r = (const float*)d_in[9];
    const float* bhh_r = (const float*)d_in[10];
    const float* Wih_p = (const float*)d_in[11];
    const float* Whh_p = (const float*)d_in[12];
    const float* bih_p = (const float*)d_in[13];
    const float* bhh_p = (const float*)d_in[14];
    const float* fcW   = (const float*)d_in[15];
    const float* fcb   = (const float*)d_in[16];
    float* out = (float*)d_out;

    char* ws = (char*)d_ws;
    size_t off = 0;
    auto alloc = [&](size_t bytes) {
        char* p = ws + off;
        off += (bytes + 255) & ~(size_t)255;
        return p;
    };
    float* attn  = (float*)alloc(2*156*156*sizeof(float));
    float* Mbuf  = (float*)alloc(2*128*156*sizeof(float));
    float* bias2 = (float*)alloc(2*128*sizeof(float));
    float* sbuf  = (float*)alloc(4*156*sizeof(float));
    float* hr_ws = (float*)alloc((size_t)BATCH*HLSTM*sizeof(float));
    float* h_ws  = (float*)alloc((size_t)BATCH*HLSTM*sizeof(float));
    float* c_ws  = (float*)alloc((size_t)BATCH*HLSTM*sizeof(float));

    int CS = 4;                                       // chunk of T steps (must divide 4)
    size_t gbytes = (size_t)BATCH*4*G4*sizeof(float); // CS=4 gate buffer
    if (off + gbytes > ws_size) { CS = 2; gbytes >>= 1; }
    if (off + gbytes > ws_size) { CS = 1; gbytes >>= 1; }
    float* gbuf = (float*)alloc(gbytes);

    k_gat_s<<<dim3(156, 2), 128, 0, stream>>>(emb, Wr, ar, Wp, ap, sbuf);
    k_attn<<<dim3(156, 2), 256, 0, stream>>>(sbuf, adj, attn);
    k_buildM<<<dim3(128, 2), 192, 0, stream>>>(attn, Wih_r, Wih_p, bih_r, bhh_r,
                                               bih_p, bhh_p, Mbuf, bias2);
    int nch = TT / CS;
    for (int c = 0; c < nch; ++c) {
        k_gates<<<dim3(BATCH/128, CS), 256, 0, stream>>>(x, Mbuf, gbuf, c*CS, CS);
        k_lstm<<<dim3(256), 256, 0, stream>>>(gbuf, Whh_r, Whh_p, bias2,
                                              h_ws, c_ws, hr_ws, fcW, fcb, out, c*CS, CS);
    }
}

// Round 2
// 111.087 us; speedup vs baseline: 4.7325x; 4.7325x over previous
//
#include <hip/hip_runtime.h>
#include <math.h>

#define N_NODES 156
#define NFEAT 256
#define NHID 128
#define BATCH 16384
#define TT 24
#define HLSTM 32
#define G4 128            // 4*HLSTM
#define ALPHA 0.2f

typedef __attribute__((ext_vector_type(8))) short bf16x8;
typedef __attribute__((ext_vector_type(4))) float f32x4;

static __device__ __forceinline__ unsigned short f2bf(float f) {
    unsigned u = __float_as_uint(f);
    u += 0x7fffu + ((u >> 16) & 1u);          // RNE
    return (unsigned short)(u >> 16);
}
static __device__ __forceinline__ unsigned pk2(float lo, float hi) {
    return (unsigned)f2bf(lo) | ((unsigned)f2bf(hi) << 16);
}
static __device__ __forceinline__ bf16x8 cvt8(float4 a, float4 b) {
    bf16x8 r;
    r[0] = (short)f2bf(a.x); r[1] = (short)f2bf(a.y);
    r[2] = (short)f2bf(a.z); r[3] = (short)f2bf(a.w);
    r[4] = (short)f2bf(b.x); r[5] = (short)f2bf(b.y);
    r[6] = (short)f2bf(b.z); r[7] = (short)f2bf(b.w);
    return r;
}
static __device__ __forceinline__ float sigm(float x) { return 1.f / (1.f + __expf(-x)); }
static __device__ __forceinline__ float tanh_(float x) { return 1.f - 2.f / (__expf(2.f * x) + 1.f); }

// ---------------- K1: GAT s1/s2 ----
__global__ void k_gat_s(const float* __restrict__ emb,
                        const float* __restrict__ Wr, const float* __restrict__ ar,
                        const float* __restrict__ Wp, const float* __restrict__ ap,
                        float* __restrict__ s_buf /* [2][2][156] */) {
    int i = blockIdx.x;
    int gat = blockIdx.y;
    const float* W = gat ? Wp : Wr;
    const float* a = gat ? ap : ar;
    int j = threadIdx.x; // 0..127
    __shared__ float erow[NFEAT];
    __shared__ float red[128];
    for (int k = j; k < NFEAT; k += 128) erow[k] = emb[i*NFEAT + k];
    __syncthreads();
    float h = 0.f;
    for (int k = 0; k < NFEAT; ++k) h = fmaf(erow[k], W[k*NHID + j], h);
    float v1 = h * a[j];
    float v2 = h * a[NHID + j];
    red[j] = v1; __syncthreads();
    for (int s = 64; s > 0; s >>= 1) { if (j < s) red[j] += red[j+s]; __syncthreads(); }
    if (j == 0) s_buf[(gat*2+0)*N_NODES + i] = red[0];
    __syncthreads();
    red[j] = v2; __syncthreads();
    for (int s = 64; s > 0; s >>= 1) { if (j < s) red[j] += red[j+s]; __syncthreads(); }
    if (j == 0) s_buf[(gat*2+1)*N_NODES + i] = red[0];
}

// ---------------- K2: masked leaky-relu softmax rows -> attn ----------------
__global__ void k_attn(const float* __restrict__ s_buf, const int* __restrict__ adj,
                       float* __restrict__ attn /* [2][156][156] */) {
    int i = blockIdx.x, gat = blockIdx.y;
    int j = threadIdx.x;
    __shared__ float red[256];
    float s1 = s_buf[(gat*2+0)*N_NODES + i];
    bool act = (j < N_NODES);
    float e = -INFINITY;
    if (act) {
        float s2 = s_buf[(gat*2+1)*N_NODES + j];
        float z = s1 + s2;
        z = (z > 0.f) ? z : ALPHA * z;
        if (adj[i*N_NODES + j] <= 0) z = -9e15f;
        e = z;
    }
    red[j] = e; __syncthreads();
    for (int s = 128; s > 0; s >>= 1) { if (j < s) red[j] = fmaxf(red[j], red[j+s]); __syncthreads(); }
    float m = red[0]; __syncthreads();
    float val = act ? __expf(e - m) : 0.f;
    red[j] = val; __syncthreads();
    for (int s = 128; s > 0; s >>= 1) { if (j < s) red[j] += red[j+s]; __syncthreads(); }
    float inv = 1.f / red[0];
    if (act) attn[(gat*N_NODES + i)*N_NODES + j] = val * inv;
}

// ---------------- K3: Mbf = bf16(Wih @ attn) zero-padded to K=160,
//                      Whhbf = bf16(Whh), bias = bih + bhh ------------------
// grid (128, 2), block 192
__global__ void k_prep(const float* __restrict__ attn,
                       const float* __restrict__ Wih_r, const float* __restrict__ Wih_p,
                       const float* __restrict__ Whh_r, const float* __restrict__ Whh_p,
                       const float* __restrict__ bih_r, const float* __restrict__ bhh_r,
                       const float* __restrict__ bih_p, const float* __restrict__ bhh_p,
                       unsigned short* __restrict__ Mbf /* [2][128][160] */,
                       unsigned short* __restrict__ Whhbf /* [2][128][32] */,
                       float* __restrict__ bias2 /* [2][128] */) {
    int g = blockIdx.x, gat = blockIdx.y;
    const float* Wih = gat ? Wih_p : Wih_r;
    const float* A = attn + gat*N_NODES*N_NODES;
    int j = threadIdx.x;
    if (j < 160) {
        float acc = 0.f;
        if (j < N_NODES)
            for (int n = 0; n < N_NODES; ++n)
                acc = fmaf(Wih[g*N_NODES + n], A[n*N_NODES + j], acc);
        Mbf[(gat*G4 + g)*160 + j] = f2bf(acc);   // j>=156 -> bf16(0) == 0
    }
    if (j < HLSTM)
        Whhbf[(gat*G4 + g)*HLSTM + j] = f2bf((gat ? Whh_p : Whh_r)[g*HLSTM + j]);
    if (g == 0 && j < G4)
        bias2[gat*G4 + j] = gat ? (bih_p[j] + bhh_p[j]) : (bih_r[j] + bhh_r[j]);
}

// ---------------- K4: fused gates-MFMA + LSTM + fc, barrier-free ------------
// grid 256, block 256 (4 waves). Each wave owns 16 batch rows for all 24 steps.
// All LDS traffic is wave-local -> no __syncthreads anywhere.
#define XS_HALF (64*160)          // ushorts per x buffer
__global__ void __launch_bounds__(256, 1)
k_fused(const float* __restrict__ x,
        const unsigned short* __restrict__ Mbf,    // [2][128][160] bf16, k-padded 0
        const unsigned short* __restrict__ Whhbf,  // [2][128][32] bf16
        const float* __restrict__ bias2,           // [2][128]
        const float* __restrict__ fcW,             // [156][64] f32
        const float* __restrict__ fcb,             // [156]
        float* __restrict__ out) {                 // [16384][156] f32
    __shared__ __align__(16) unsigned short xs[2*XS_HALF];  // [2][64][160] bf16
    __shared__ __align__(16) unsigned short hs[64*40];      // [64][40] bf16 (cols 0..31 used)
    __shared__ __align__(16) unsigned short hcat[64*72];    // [64][72] bf16 (cols 0..63 = hr|hp)

    const int tid = threadIdx.x;
    const int w  = tid >> 6;          // wave 0..3
    const int l  = tid & 63;
    const int lm = l & 15;            // MFMA m/n-within-tile & D-col
    const int lg = l >> 4;            // MFMA k-group & D-row-group
    const int brow = tid >> 2;        // staging row 0..63 (wave-local: 16w..16w+15)
    const int q    = tid & 3;         // staging quarter of a row
    const int nf   = (q == 3) ? 9 : 10;
    const int b0 = blockIdx.x * 64;

    // ---- fragments in registers (reloaded at t==4 switch) ----
    bf16x8 bfr[8][5];     // gates B: [n-tile][k-frag]
    bf16x8 wrec[8];       // rec B
    float  bias_v[8];
    float  cst[8];        // c-state: [ds*4 + i]

#define LOAD_FRAGS(Mb, Wb, bs) do {                                          \
    _Pragma("unroll")                                                        \
    for (int nt = 0; nt < 8; ++nt) {                                         \
        int n_ = nt*16 + lm;                                                 \
        _Pragma("unroll")                                                    \
        for (int kf = 0; kf < 5; ++kf)                                       \
            bfr[nt][kf] = *(const bf16x8*)((Mb) + n_*160 + kf*32 + lg*8);    \
        wrec[nt]   = *(const bf16x8*)((Wb) + n_*HLSTM + lg*8);               \
        bias_v[nt] = (bs)[n_];                                               \
    } } while (0)

    // ---- init: zero x-pad cols (k=156..159), zero h, load recent frags ----
    if (q == 3) {
        *(uint2*)(xs + 0*XS_HALF + brow*160 + 156) = make_uint2(0u, 0u);
        *(uint2*)(xs + 1*XS_HALF + brow*160 + 156) = make_uint2(0u, 0u);
    }
    #pragma unroll
    for (int ds = 0; ds < 2; ++ds)
        #pragma unroll
        for (int i = 0; i < 4; ++i) {
            hs[(16*w + lg*4 + i)*40 + lm + 16*ds] = 0;
            cst[ds*4 + i] = 0.f;
        }
    LOAD_FRAGS(Mbf, Whhbf, bias2);

    float4 st[10];
    // prologue: stage t=0 into buf0
    {
        const float* gp = x + ((size_t)(b0 + brow)*TT + 0)*N_NODES + q*40;
        #pragma unroll
        for (int i = 0; i < 10; ++i) if (i < nf) st[i] = ((const float4*)gp)[i];
        unsigned short* xw = xs + 0*XS_HALF + brow*160 + q*40;
        #pragma unroll
        for (int i = 0; i < 10; ++i) if (i < nf) {
            uint2 p; p.x = pk2(st[i].x, st[i].y); p.y = pk2(st[i].z, st[i].w);
            *(uint2*)(xw + i*4) = p;
        }
    }

    #pragma unroll 2
    for (int t = 0; t < TT; ++t) {
        const int cur = t & 1;
        // T14: issue next-step global loads early; LDS-write after compute
        if (t < TT-1) {
            const float* gp = x + ((size_t)(b0 + brow)*TT + (t+1))*N_NODES + q*40;
            #pragma unroll
            for (int i = 0; i < 10; ++i) if (i < nf) st[i] = ((const float4*)gp)[i];
        }

        // gates_in + rec, accumulated in MFMA
        f32x4 acc[8];
        #pragma unroll
        for (int nt = 0; nt < 8; ++nt) acc[nt] = (f32x4){0.f, 0.f, 0.f, 0.f};
        #pragma unroll
        for (int kf = 0; kf < 5; ++kf) {
            bf16x8 af = *(const bf16x8*)(xs + cur*XS_HALF + (16*w + lm)*160 + kf*32 + lg*8);
            #pragma unroll
            for (int nt = 0; nt < 8; ++nt)
                acc[nt] = __builtin_amdgcn_mfma_f32_16x16x32_bf16(af, bfr[nt][kf], acc[nt], 0, 0, 0);
        }
        {
            bf16x8 hf = *(const bf16x8*)(hs + (16*w + lm)*40 + lg*8);
            #pragma unroll
            for (int nt = 0; nt < 8; ++nt)
                acc[nt] = __builtin_amdgcn_mfma_f32_16x16x32_bf16(hf, wrec[nt], acc[nt], 0, 0, 0);
        }

        // pointwise LSTM cell; thread holds rows 16w+lg*4+i, cols lm & lm+16
        #pragma unroll
        for (int ds = 0; ds < 2; ++ds)
            #pragma unroll
            for (int i = 0; i < 4; ++i) {
                float gi = acc[0 + ds][i] + bias_v[0 + ds];
                float gf = acc[2 + ds][i] + bias_v[2 + ds];
                float gg = acc[4 + ds][i] + bias_v[4 + ds];
                float go = acc[6 + ds][i] + bias_v[6 + ds];
                float si = sigm(gi), sf = sigm(gf), so = sigm(go);
                float c  = sf * cst[ds*4 + i] + si * tanh_(gg);
                float h  = so * tanh_(c);
                int r = 16*w + lg*4 + i;
                int d = lm + 16*ds;
                if (t == 3) {                  // end of recent LSTM: stash h_r, reset state
                    hcat[r*72 + d] = f2bf(h);
                    hs[r*40 + d]   = 0;
                    cst[ds*4 + i]  = 0.f;
                } else {
                    cst[ds*4 + i] = c;
                    hs[r*40 + d]  = f2bf(h);
                    if (t == TT-1) hcat[r*72 + 32 + d] = f2bf(h);
                }
            }

        if (t == 3)   // switch to period-LSTM weights
            LOAD_FRAGS(Mbf + G4*160, Whhbf + G4*HLSTM, bias2 + G4);

        if (t < TT-1) {
            unsigned short* xw = xs + (cur ^ 1)*XS_HALF + brow*160 + q*40;
            #pragma unroll
            for (int i = 0; i < 10; ++i) if (i < nf) {
                uint2 p; p.x = pk2(st[i].x, st[i].y); p.y = pk2(st[i].z, st[i].w);
                *(uint2*)(xw + i*4) = p;
            }
        }
    }

    // ---- fc epilogue: out = [hr|hp] @ fcW^T + fcb (MFMA, K=64) ----
    {
        bf16x8 ha0 = *(const bf16x8*)(hcat + (16*w + lm)*72 + lg*8);
        bf16x8 ha1 = *(const bf16x8*)(hcat + (16*w + lm)*72 + 32 + lg*8);
        #pragma unroll
        for (int nt = 0; nt < 10; ++nt) {
            int n  = nt*16 + lm;
            int nc = n < 155 ? n : 155;
            const float* wp0 = fcW + nc*64 + lg*8;
            const float* wp1 = fcW + nc*64 + 32 + lg*8;
            bf16x8 wf0 = cvt8(*(const float4*)wp0, *(const float4*)(wp0 + 4));
            bf16x8 wf1 = cvt8(*(const float4*)wp1, *(const float4*)(wp1 + 4));
            f32x4 fa = (f32x4){0.f, 0.f, 0.f, 0.f};
            fa = __builtin_amdgcn_mfma_f32_16x16x32_bf16(ha0, wf0, fa, 0, 0, 0);
            fa = __builtin_amdgcn_mfma_f32_16x16x32_bf16(ha1, wf1, fa, 0, 0, 0);
            if (n < N_NODES) {
                float bn = fcb[n];
                #pragma unroll
                for (int i = 0; i < 4; ++i)
                    out[(size_t)(b0 + 16*w + lg*4 + i)*N_NODES + n] = fa[i] + bn;
            }
        }
    }
#undef LOAD_FRAGS
}

extern "C" void kernel_launch(void* const* d_in, const int* in_sizes, int n_in,
                              void* d_out, int out_size, void* d_ws, size_t ws_size,
                              hipStream_t stream) {
    (void)in_sizes; (void)n_in; (void)out_size; (void)ws_size;
    const float* emb   = (const float*)d_in[0];
    const float* x     = (const float*)d_in[1];
    const int*   adj   = (const int*)d_in[2];
    const float* Wr    = (const float*)d_in[3];
    const float* ar    = (const float*)d_in[4];
    const float* Wp    = (const float*)d_in[5];
    const float* ap    = (const float*)d_in[6];
    const float* Wih_r = (const float*)d_in[7];
    const float* Whh_r = (const float*)d_in[8];
    const float* bih_r = (const float*)d_in[9];
    const float* bhh_r = (const float*)d_in[10];
    const float* Wih_p = (const float*)d_in[11];
    const float* Whh_p = (const float*)d_in[12];
    const float* bih_p = (const float*)d_in[13];
    const float* bhh_p = (const float*)d_in[14];
    const float* fcW   = (const float*)d_in[15];
    const float* fcb   = (const float*)d_in[16];
    float* out = (float*)d_out;

    char* ws = (char*)d_ws;
    size_t off = 0;
    auto alloc = [&](size_t bytes) {
        char* p = ws + off;
        off += (bytes + 255) & ~(size_t)255;
        return p;
    };
    float*          attn  = (float*)alloc(2*156*156*sizeof(float));
    float*          sbuf  = (float*)alloc(4*156*sizeof(float));
    unsigned short* Mbf   = (unsigned short*)alloc(2*G4*160*sizeof(unsigned short));
    unsigned short* Whhbf = (unsigned short*)alloc(2*G4*HLSTM*sizeof(unsigned short));
    float*          bias2 = (float*)alloc(2*G4*sizeof(float));

    k_gat_s<<<dim3(156, 2), 128, 0, stream>>>(emb, Wr, ar, Wp, ap, sbuf);
    k_attn<<<dim3(156, 2), 256, 0, stream>>>(sbuf, adj, attn);
    k_prep<<<dim3(128, 2), 192, 0, stream>>>(attn, Wih_r, Wih_p, Whh_r, Whh_p,
                                             bih_r, bhh_r, bih_p, bhh_p,
                                             Mbf, Whhbf, bias2);
    k_fused<<<dim3(256), 256, 0, stream>>>(x, Mbf, Whhbf, bias2, fcW, fcb, out);
}

// Round 4
// 97.618 us; speedup vs baseline: 5.3855x; 1.1380x over previous
//
#include <hip/hip_runtime.h>
#include <hip/hip_bf16.h>
#include <math.h>

#define N_NODES 156
#define NFEAT 256
#define NHID 128
#define BATCH 16384
#define TT 24
#define HLSTM 32
#define G4 128            // 4*HLSTM
#define ALPHA 0.2f
#define NW 2              // waves per block
#define ROWS_B (NW*16)    // batch rows per block

typedef __attribute__((ext_vector_type(8))) short bf16x8;
typedef __attribute__((ext_vector_type(4))) float f32x4;

static __device__ __forceinline__ unsigned short f2bf(float f) {
    unsigned u = __float_as_uint(f);
    u += 0x7fffu + ((u >> 16) & 1u);          // RNE
    return (unsigned short)(u >> 16);
}
static __device__ __forceinline__ bf16x8 cv8(float4 a, float4 b) {
    union { __hip_bfloat16 h[8]; bf16x8 v; } u;
    u.h[0] = __float2bfloat16(a.x); u.h[1] = __float2bfloat16(a.y);
    u.h[2] = __float2bfloat16(a.z); u.h[3] = __float2bfloat16(a.w);
    u.h[4] = __float2bfloat16(b.x); u.h[5] = __float2bfloat16(b.y);
    u.h[6] = __float2bfloat16(b.z); u.h[7] = __float2bfloat16(b.w);
    return u.v;
}
static __device__ __forceinline__ float sigm(float x) { return 1.f / (1.f + __expf(-x)); }
static __device__ __forceinline__ float tanh_(float x) { return 1.f - 2.f / (__expf(2.f * x) + 1.f); }

// ---------------- K1: GAT s1/s2 ----
__global__ void k_gat_s(const float* __restrict__ emb,
                        const float* __restrict__ Wr, const float* __restrict__ ar,
                        const float* __restrict__ Wp, const float* __restrict__ ap,
                        float* __restrict__ s_buf /* [2][2][156] */) {
    int i = blockIdx.x;
    int gat = blockIdx.y;
    const float* W = gat ? Wp : Wr;
    const float* a = gat ? ap : ar;
    int j = threadIdx.x; // 0..127
    __shared__ float erow[NFEAT];
    __shared__ float red[128];
    for (int k = j; k < NFEAT; k += 128) erow[k] = emb[i*NFEAT + k];
    __syncthreads();
    float h = 0.f;
    for (int k = 0; k < NFEAT; ++k) h = fmaf(erow[k], W[k*NHID + j], h);
    float v1 = h * a[j];
    float v2 = h * a[NHID + j];
    red[j] = v1; __syncthreads();
    for (int s = 64; s > 0; s >>= 1) { if (j < s) red[j] += red[j+s]; __syncthreads(); }
    if (j == 0) s_buf[(gat*2+0)*N_NODES + i] = red[0];
    __syncthreads();
    red[j] = v2; __syncthreads();
    for (int s = 64; s > 0; s >>= 1) { if (j < s) red[j] += red[j+s]; __syncthreads(); }
    if (j == 0) s_buf[(gat*2+1)*N_NODES + i] = red[0];
}

// ---------------- K2: masked leaky-relu softmax rows -> attn ----------------
__global__ void k_attn(const float* __restrict__ s_buf, const int* __restrict__ adj,
                       float* __restrict__ attn /* [2][156][156] */) {
    int i = blockIdx.x, gat = blockIdx.y;
    int j = threadIdx.x;
    __shared__ float red[256];
    float s1 = s_buf[(gat*2+0)*N_NODES + i];
    bool act = (j < N_NODES);
    float e = -INFINITY;
    if (act) {
        float s2 = s_buf[(gat*2+1)*N_NODES + j];
        float z = s1 + s2;
        z = (z > 0.f) ? z : ALPHA * z;
        if (adj[i*N_NODES + j] <= 0) z = -9e15f;
        e = z;
    }
    red[j] = e; __syncthreads();
    for (int s = 128; s > 0; s >>= 1) { if (j < s) red[j] = fmaxf(red[j], red[j+s]); __syncthreads(); }
    float m = red[0]; __syncthreads();
    float val = act ? __expf(e - m) : 0.f;
    red[j] = val; __syncthreads();
    for (int s = 128; s > 0; s >>= 1) { if (j < s) red[j] += red[j+s]; __syncthreads(); }
    float inv = 1.f / red[0];
    if (act) attn[(gat*N_NODES + i)*N_NODES + j] = val * inv;
}

// ---------------- K3: Mbf = bf16(Wih @ attn) zero-padded to K=160,
//                      Whhbf = bf16(Whh), bias = bih + bhh ------------------
__global__ void k_prep(const float* __restrict__ attn,
                       const float* __restrict__ Wih_r, const float* __restrict__ Wih_p,
                       const float* __restrict__ Whh_r, const float* __restrict__ Whh_p,
                       const float* __restrict__ bih_r, const float* __restrict__ bhh_r,
                       const float* __restrict__ bih_p, const float* __restrict__ bhh_p,
                       unsigned short* __restrict__ Mbf /* [2][128][160] */,
                       unsigned short* __restrict__ Whhbf /* [2][128][32] */,
                       float* __restrict__ bias2 /* [2][128] */) {
    int g = blockIdx.x, gat = blockIdx.y;
    const float* Wih = gat ? Wih_p : Wih_r;
    const float* A = attn + gat*N_NODES*N_NODES;
    int j = threadIdx.x;
    if (j < 160) {
        float acc = 0.f;
        if (j < N_NODES)
            for (int n = 0; n < N_NODES; ++n)
                acc = fmaf(Wih[g*N_NODES + n], A[n*N_NODES + j], acc);
        Mbf[(gat*G4 + g)*160 + j] = f2bf(acc);   // j>=156 -> 0
    }
    if (j < HLSTM)
        Whhbf[(gat*G4 + g)*HLSTM + j] = f2bf((gat ? Whh_p : Whh_r)[g*HLSTM + j]);
    if (g == 0 && j < G4)
        bias2[gat*G4 + j] = gat ? (bih_p[j] + bhh_p[j]) : (bih_r[j] + bhh_r[j]);
}

// ---------------- K4: fused gates-MFMA + LSTM + fc, barrier-free ------------
// grid 512, block 128 (2 waves). Each wave owns 16 batch rows for all 24 steps.
// All LDS regions are per-wave and stored in MFMA-FRAGMENT-LINEAR order:
// every ds_read/ds_write is lane-linear 16B (bank-optimal, no conflicts).
#define XS_W (5*64*8)             // ushorts per wave per buffer (5 kf-slots)
#define XS_B (NW*XS_W)            // ushorts per buffer
__global__ void __launch_bounds__(NW*64, 1)
k_fused(const float* __restrict__ x,
        const unsigned short* __restrict__ Mbf,    // [2][128][160] bf16, k-padded 0
        const unsigned short* __restrict__ Whhbf,  // [2][128][32] bf16
        const float* __restrict__ bias2,           // [2][128]
        const float* __restrict__ fcW,             // [156][64] f32
        const float* __restrict__ fcb,             // [156]
        float* __restrict__ out) {                 // [16384][156] f32
    __shared__ __align__(16) unsigned short xs[2*XS_B];     // x frags, dbuf
    __shared__ __align__(16) unsigned short hfrag[NW*512];  // h frags
    __shared__ __align__(16) unsigned short hcatf[NW*1024]; // [w][half][64][8] hr|hp frags

    const int tid = threadIdx.x;
    const int w  = tid >> 6;          // wave 0..NW-1
    const int l  = tid & 63;
    const int lm = l & 15;            // MFMA row-within-tile (A) / col (D)
    const int lg = l >> 4;            // MFMA k-group / D-row-group
    const int b0 = blockIdx.x * ROWS_B;
    const size_t xrow = (size_t)(b0 + 16*w + lm) * (TT*N_NODES);

    bf16x8 bfr[8][5];     // gates B: [n-tile][k-frag]
    bf16x8 wrec[8];       // rec B
    float  bias_v[8];
    float  cst[8];        // c-state

#define LOAD_FRAGS(Mb, Wb, bs) do {                                          \
    _Pragma("unroll")                                                        \
    for (int nt = 0; nt < 8; ++nt) {                                         \
        int n_ = nt*16 + lm;                                                 \
        _Pragma("unroll")                                                    \
        for (int kf = 0; kf < 5; ++kf)                                       \
            bfr[nt][kf] = *(const bf16x8*)((Mb) + n_*160 + kf*32 + lg*8);    \
        wrec[nt]   = *(const bf16x8*)((Wb) + n_*HLSTM + lg*8);               \
        bias_v[nt] = (bs)[n_];                                               \
    } } while (0)

    // zero h-state (each thread covers its own 8 cells -> full 16x32 per wave)
    #pragma unroll
    for (int ds = 0; ds < 2; ++ds)
        #pragma unroll
        for (int i = 0; i < 4; ++i) {
            hfrag[w*512 + ((lm>>3) + 2*ds)*128 + (lg*4 + i)*8 + (lm&7)] = 0;
            cst[ds*4 + i] = 0.f;
        }
    LOAD_FRAGS(Mbf, Whhbf, bias2);

    float4 fA[10], fB[10];
    const float4 f4z = make_float4(0.f, 0.f, 0.f, 0.f);

    // issue the 10 global float4 loads of x(TL) into register bank F
    // (lane loads exactly its own MFMA A-fragment source: row lm, k = kf*32+lg*8)
#define ISSUE(F, TL) do {                                                    \
    const float* bp_ = x + xrow + (size_t)(TL)*N_NODES + lg*8;               \
    _Pragma("unroll")                                                        \
    for (int kf = 0; kf < 5; ++kf) {                                         \
        F[2*kf]   = *(const float4*)(bp_ + kf*32);                           \
        F[2*kf+1] = (kf == 4 && lg == 3) ? f4z                               \
                                         : *(const float4*)(bp_ + kf*32 + 4);\
    } } while (0)

    // convert bank F to bf16 frags and write lane-linear into xs buffer NB
#define CVTW(F, NB) do {                                                     \
    unsigned short* xw_ = xs + (NB)*XS_B + w*XS_W + l*8;                     \
    _Pragma("unroll")                                                        \
    for (int kf = 0; kf < 5; ++kf)                                           \
        *(bf16x8*)(xw_ + kf*512) = cv8(F[2*kf], F[2*kf+1]);                  \
    } while (0)

    ISSUE(fA, 0);
    ISSUE(fB, 1);
    CVTW(fA, 0);

#define STEP(T_, FC, FN) do {                                                \
    if ((T_) + 2 < TT) ISSUE(FN, (T_) + 2);                                  \
    if ((T_) + 1 < TT) CVTW(FC, ((T_) + 1) & 1);  /* FC holds x(T_+1) */     \
    f32x4 acc[8];                                                            \
    _Pragma("unroll")                                                        \
    for (int nt = 0; nt < 8; ++nt)                                           \
        acc[nt] = (f32x4){bias_v[nt], bias_v[nt], bias_v[nt], bias_v[nt]};   \
    { const unsigned short* xr_ = xs + ((T_)&1)*XS_B + w*XS_W + l*8;         \
      _Pragma("unroll")                                                      \
      for (int kf = 0; kf < 5; ++kf) {                                       \
          bf16x8 af = *(const bf16x8*)(xr_ + kf*512);                        \
          _Pragma("unroll")                                                  \
          for (int nt = 0; nt < 8; ++nt)                                     \
              acc[nt] = __builtin_amdgcn_mfma_f32_16x16x32_bf16(af, bfr[nt][kf], acc[nt], 0, 0, 0); \
      }                                                                      \
      bf16x8 hf = *(const bf16x8*)(hfrag + w*512 + l*8);                     \
      _Pragma("unroll")                                                      \
      for (int nt = 0; nt < 8; ++nt)                                         \
          acc[nt] = __builtin_amdgcn_mfma_f32_16x16x32_bf16(hf, wrec[nt], acc[nt], 0, 0, 0); \
    }                                                                        \
    _Pragma("unroll")                                                        \
    for (int ds = 0; ds < 2; ++ds)                                           \
        _Pragma("unroll")                                                    \
        for (int i = 0; i < 4; ++i) {                                        \
            float si = sigm(acc[0 + ds][i]);                                 \
            float sf = sigm(acc[2 + ds][i]);                                 \
            float tg = tanh_(acc[4 + ds][i]);                                \
            float so = sigm(acc[6 + ds][i]);                                 \
            float c  = sf * cst[ds*4 + i] + si * tg;                         \
            float h  = so * tanh_(c);                                        \
            int cidx = ((lm>>3) + 2*ds)*128 + (lg*4 + i)*8 + (lm&7);         \
            if ((T_) == 3) {              /* end recent: stash h_r, reset */ \
                hcatf[w*1024 + cidx] = f2bf(h);                              \
                hfrag[w*512 + cidx]  = 0;                                    \
                cst[ds*4 + i] = 0.f;                                         \
            } else {                                                         \
                cst[ds*4 + i] = c;                                           \
                hfrag[w*512 + cidx] = f2bf(h);                               \
                if ((T_) == TT-1) hcatf[w*1024 + 512 + cidx] = f2bf(h);      \
            }                                                                \
        }                                                                    \
    if ((T_) == 3) LOAD_FRAGS(Mbf + G4*160, Whhbf + G4*HLSTM, bias2 + G4);   \
    } while (0)

    for (int t = 0; t < TT; t += 2) {
        STEP(t,     fB, fA);
        STEP(t + 1, fA, fB);
    }

    // ---- fc epilogue: out = [hr|hp] @ fcW^T + fcb (MFMA, K=64) ----
    {
        bf16x8 ha0 = *(const bf16x8*)(hcatf + w*1024 + l*8);
        bf16x8 ha1 = *(const bf16x8*)(hcatf + w*1024 + 512 + l*8);
        #pragma unroll
        for (int nt = 0; nt < 10; ++nt) {
            int n  = nt*16 + lm;
            int nc = n < 155 ? n : 155;
            const float* wp0 = fcW + nc*64 + lg*8;
            const float* wp1 = fcW + nc*64 + 32 + lg*8;
            bf16x8 wf0 = cv8(*(const float4*)wp0, *(const float4*)(wp0 + 4));
            bf16x8 wf1 = cv8(*(const float4*)wp1, *(const float4*)(wp1 + 4));
            f32x4 fa = (f32x4){0.f, 0.f, 0.f, 0.f};
            fa = __builtin_amdgcn_mfma_f32_16x16x32_bf16(ha0, wf0, fa, 0, 0, 0);
            fa = __builtin_amdgcn_mfma_f32_16x16x32_bf16(ha1, wf1, fa, 0, 0, 0);
            if (n < N_NODES) {
                float bn = fcb[n];
                #pragma unroll
                for (int i = 0; i < 4; ++i)
                    out[(size_t)(b0 + 16*w + lg*4 + i)*N_NODES + n] = fa[i] + bn;
            }
        }
    }
#undef STEP
#undef CVTW
#undef ISSUE
#undef LOAD_FRAGS
}

extern "C" void kernel_launch(void* const* d_in, const int* in_sizes, int n_in,
                              void* d_out, int out_size, void* d_ws, size_t ws_size,
                              hipStream_t stream) {
    (void)in_sizes; (void)n_in; (void)out_size; (void)ws_size;
    const float* emb   = (const float*)d_in[0];
    const float* x     = (const float*)d_in[1];
    const int*   adj   = (const int*)d_in[2];
    const float* Wr    = (const float*)d_in[3];
    const float* ar    = (const float*)d_in[4];
    const float* Wp    = (const float*)d_in[5];
    const float* ap    = (const float*)d_in[6];
    const float* Wih_r = (const float*)d_in[7];
    const float* Whh_r = (const float*)d_in[8];
    const float* bih_r = (const float*)d_in[9];
    const float* bhh_r = (const float*)d_in[10];
    const float* Wih_p = (const float*)d_in[11];
    const float* Whh_p = (const float*)d_in[12];
    const float* bih_p = (const float*)d_in[13];
    const float* bhh_p = (const float*)d_in[14];
    const float* fcW   = (const float*)d_in[15];
    const float* fcb   = (const float*)d_in[16];
    float* out = (float*)d_out;

    char* ws = (char*)d_ws;
    size_t off = 0;
    auto alloc = [&](size_t bytes) {
        char* p = ws + off;
        off += (bytes + 255) & ~(size_t)255;
        return p;
    };
    float*          attn  = (float*)alloc(2*156*156*sizeof(float));
    float*          sbuf  = (float*)alloc(4*156*sizeof(float));
    unsigned short* Mbf   = (unsigned short*)alloc(2*G4*160*sizeof(unsigned short));
    unsigned short* Whhbf = (unsigned short*)alloc(2*G4*HLSTM*sizeof(unsigned short));
    float*          bias2 = (float*)alloc(2*G4*sizeof(float));

    k_gat_s<<<dim3(156, 2), 128, 0, stream>>>(emb, Wr, ar, Wp, ap, sbuf);
    k_attn<<<dim3(156, 2), 256, 0, stream>>>(sbuf, adj, attn);
    k_prep<<<dim3(128, 2), 192, 0, stream>>>(attn, Wih_r, Wih_p, Whh_r, Whh_p,
                                             bih_r, bhh_r, bih_p, bhh_p,
                                             Mbf, Whhbf, bias2);
    k_fused<<<dim3(BATCH/ROWS_B), NW*64, 0, stream>>>(x, Mbf, Whhbf, bias2, fcW, fcb, out);
}

// Round 5
// 94.185 us; speedup vs baseline: 5.5818x; 1.0364x over previous
//
#include <hip/hip_runtime.h>
#include <hip/hip_bf16.h>
#include <math.h>

#define N_NODES 156
#define NFEAT 256
#define NHID 128
#define BATCH 16384
#define TT 24
#define HLSTM 32
#define G4 128            // 4*HLSTM
#define ALPHA 0.2f
#define NW 2              // waves per block
#define ROWS_B (NW*16)    // batch rows per block
#define XSTRIDE (TT*N_NODES)   // 3744 floats per batch row
#define SLOTF 2560        // floats per (wave, time-slot) LDS x-image (10240 B)

typedef __attribute__((ext_vector_type(8))) short bf16x8;
typedef __attribute__((ext_vector_type(4))) float f32x4;

static __device__ __forceinline__ unsigned short f2bf(float f) {
    unsigned u = __float_as_uint(f);
    u += 0x7fffu + ((u >> 16) & 1u);          // RNE
    return (unsigned short)(u >> 16);
}
static __device__ __forceinline__ bf16x8 cv8(float4 a, float4 b) {
    union { __hip_bfloat16 h[8]; bf16x8 v; } u;
    u.h[0] = __float2bfloat16(a.x); u.h[1] = __float2bfloat16(a.y);
    u.h[2] = __float2bfloat16(a.z); u.h[3] = __float2bfloat16(a.w);
    u.h[4] = __float2bfloat16(b.x); u.h[5] = __float2bfloat16(b.y);
    u.h[6] = __float2bfloat16(b.z); u.h[7] = __float2bfloat16(b.w);
    return u.v;
}
static __device__ __forceinline__ float sigm(float x) { return 1.f / (1.f + __expf(-x)); }
static __device__ __forceinline__ float tanh_(float x) { return 1.f - 2.f / (__expf(2.f * x) + 1.f); }

// ---------------- K1: GAT s1/s2 ----
__global__ void k_gat_s(const float* __restrict__ emb,
                        const float* __restrict__ Wr, const float* __restrict__ ar,
                        const float* __restrict__ Wp, const float* __restrict__ ap,
                        float* __restrict__ s_buf /* [2][2][156] */) {
    int i = blockIdx.x;
    int gat = blockIdx.y;
    const float* W = gat ? Wp : Wr;
    const float* a = gat ? ap : ar;
    int j = threadIdx.x; // 0..127
    __shared__ float erow[NFEAT];
    __shared__ float red[128];
    for (int k = j; k < NFEAT; k += 128) erow[k] = emb[i*NFEAT + k];
    __syncthreads();
    float h = 0.f;
    for (int k = 0; k < NFEAT; ++k) h = fmaf(erow[k], W[k*NHID + j], h);
    float v1 = h * a[j];
    float v2 = h * a[NHID + j];
    red[j] = v1; __syncthreads();
    for (int s = 64; s > 0; s >>= 1) { if (j < s) red[j] += red[j+s]; __syncthreads(); }
    if (j == 0) s_buf[(gat*2+0)*N_NODES + i] = red[0];
    __syncthreads();
    red[j] = v2; __syncthreads();
    for (int s = 64; s > 0; s >>= 1) { if (j < s) red[j] += red[j+s]; __syncthreads(); }
    if (j == 0) s_buf[(gat*2+1)*N_NODES + i] = red[0];
}

// ---------------- K2: masked leaky-relu softmax rows -> attn ----------------
__global__ void k_attn(const float* __restrict__ s_buf, const int* __restrict__ adj,
                       float* __restrict__ attn /* [2][156][156] */) {
    int i = blockIdx.x, gat = blockIdx.y;
    int j = threadIdx.x;
    __shared__ float red[256];
    float s1 = s_buf[(gat*2+0)*N_NODES + i];
    bool act = (j < N_NODES);
    float e = -INFINITY;
    if (act) {
        float s2 = s_buf[(gat*2+1)*N_NODES + j];
        float z = s1 + s2;
        z = (z > 0.f) ? z : ALPHA * z;
        if (adj[i*N_NODES + j] <= 0) z = -9e15f;
        e = z;
    }
    red[j] = e; __syncthreads();
    for (int s = 128; s > 0; s >>= 1) { if (j < s) red[j] = fmaxf(red[j], red[j+s]); __syncthreads(); }
    float m = red[0]; __syncthreads();
    float val = act ? __expf(e - m) : 0.f;
    red[j] = val; __syncthreads();
    for (int s = 128; s > 0; s >>= 1) { if (j < s) red[j] += red[j+s]; __syncthreads(); }
    float inv = 1.f / red[0];
    if (act) attn[(gat*N_NODES + i)*N_NODES + j] = val * inv;
}

// ---------------- K3: Mbf = bf16(Wih @ attn) zero-padded to K=160,
//                      Whhbf = bf16(Whh), bias = bih + bhh ------------------
__global__ void k_prep(const float* __restrict__ attn,
                       const float* __restrict__ Wih_r, const float* __restrict__ Wih_p,
                       const float* __restrict__ Whh_r, const float* __restrict__ Whh_p,
                       const float* __restrict__ bih_r, const float* __restrict__ bhh_r,
                       const float* __restrict__ bih_p, const float* __restrict__ bhh_p,
                       unsigned short* __restrict__ Mbf /* [2][128][160] */,
                       unsigned short* __restrict__ Whhbf /* [2][128][32] */,
                       float* __restrict__ bias2 /* [2][128] */) {
    int g = blockIdx.x, gat = blockIdx.y;
    const float* Wih = gat ? Wih_p : Wih_r;
    const float* A = attn + gat*N_NODES*N_NODES;
    int j = threadIdx.x;
    if (j < 160) {
        float acc = 0.f;
        if (j < N_NODES)
            for (int n = 0; n < N_NODES; ++n)
                acc = fmaf(Wih[g*N_NODES + n], A[n*N_NODES + j], acc);
        Mbf[(gat*G4 + g)*160 + j] = f2bf(acc);   // j>=156 -> 0
    }
    if (j < HLSTM)
        Whhbf[(gat*G4 + g)*HLSTM + j] = f2bf((gat ? Whh_p : Whh_r)[g*HLSTM + j]);
    if (g == 0 && j < G4)
        bias2[gat*G4 + j] = gat ? (bih_p[j] + bhh_p[j]) : (bih_r[j] + bhh_r[j]);
}

// ---------------- K4: fused gates-MFMA + LSTM + fc --------------------------
// grid 512, block 128 (2 waves). Wave owns 16 batch rows for all 24 steps.
// x staged in LDS as f32 via global_load_lds DMA, depth-3 time-slot pipeline,
// counted s_waitcnt vmcnt(20) (never 0 mid-loop). Barrier-free (all wave-local).
__global__ void __launch_bounds__(NW*64, 1)
k_fused(const float* __restrict__ x,
        const unsigned short* __restrict__ Mbf,    // [2][128][160] bf16, k-padded 0
        const unsigned short* __restrict__ Whhbf,  // [2][128][32] bf16
        const float* __restrict__ bias2,           // [2][128]
        const float* __restrict__ fcW,             // [156][64] f32
        const float* __restrict__ fcb,             // [156]
        float* __restrict__ out) {                 // [16384][156] f32
    __shared__ __align__(16) float xsf[NW][3][SLOTF];        // 61.4 KB
    __shared__ __align__(16) unsigned short hfrag[NW*512];   // h frags
    __shared__ __align__(16) unsigned short hcatf[NW*1024];  // hr|hp frags

    const int tid = threadIdx.x;
    const int w  = tid >> 6;          // wave
    const int l  = tid & 63;
    const int lm = l & 15;            // MFMA A-row / D-col
    const int lg = l >> 4;            // MFMA k-group / D-row-group
    const int b0 = blockIdx.x * ROWS_B;

    // per-thread DMA source float-offsets: chunk c = l + i*64 of the packed
    // (row 0..15) x (39 chunks of 16B) space; rows clamped (tail chunks unused)
    unsigned goff[10];
    #pragma unroll
    for (int i = 0; i < 10; ++i) {
        int c = l + i*64;
        int r = c / 39;
        int cf = (c - r*39) * 4;
        if (r > 15) r = 15;
        goff[i] = (unsigned)(r*XSTRIDE + cf);
    }
    const float* xg = x + (size_t)(b0 + 16*w) * XSTRIDE;

    bf16x8 bfr[8][5];     // gates B: [n-tile][k-frag]
    bf16x8 wrec[8];       // rec B
    float  bias_v[8];
    float  cst[8];        // c-state
    const float4 f4z = make_float4(0.f, 0.f, 0.f, 0.f);

#define LOAD_FRAGS(Mb, Wb, bs) do {                                          \
    _Pragma("unroll")                                                        \
    for (int nt = 0; nt < 8; ++nt) {                                         \
        int n_ = nt*16 + lm;                                                 \
        _Pragma("unroll")                                                    \
        for (int kf = 0; kf < 5; ++kf)                                       \
            bfr[nt][kf] = *(const bf16x8*)((Mb) + n_*160 + kf*32 + lg*8);    \
        wrec[nt]   = *(const bf16x8*)((Wb) + n_*HLSTM + lg*8);               \
        bias_v[nt] = (bs)[n_];                                               \
    } } while (0)

    // zero h-state
    #pragma unroll
    for (int ds = 0; ds < 2; ++ds)
        #pragma unroll
        for (int i = 0; i < 4; ++i) {
            hfrag[w*512 + ((lm>>3) + 2*ds)*128 + (lg*4 + i)*8 + (lm&7)] = 0;
            cst[ds*4 + i] = 0.f;
        }
    LOAD_FRAGS(Mbf, Whhbf, bias2);

    // DMA one time-step into slot S_: 10 x (64 lanes x 16B), dest chunk-linear
#define DMA_STEP(S_, T_) do {                                                 \
    const float* gp_ = xg + (T_)*N_NODES;                                     \
    _Pragma("unroll")                                                         \
    for (int i_ = 0; i_ < 10; ++i_)                                           \
        __builtin_amdgcn_global_load_lds(                                     \
            (const __attribute__((address_space(1))) void*)(gp_ + goff[i_]),  \
            (__attribute__((address_space(3))) void*)(&xsf[w][S_][i_*256]),   \
            16, 0, 0);                                                        \
    } while (0)

#define WAITVM(N_) asm volatile("s_waitcnt vmcnt(" #N_ ")" ::: "memory")

#define STEP(S_, T_, ISS_, TN_) do {                                          \
    const float* xr_ = &xsf[w][S_][0] + lm*N_NODES + lg*8;                    \
    float4 q0_[5], q1_[5];                                                    \
    _Pragma("unroll")                                                         \
    for (int kf = 0; kf < 5; ++kf) {                                          \
        q0_[kf] = *(const float4*)(xr_ + kf*32);                              \
        q1_[kf] = *(const float4*)(xr_ + kf*32 + 4);                          \
    }                                                                         \
    bf16x8 hf_ = *(const bf16x8*)(hfrag + w*512 + l*8);                       \
    if (lg == 3) q1_[4] = f4z;   /* zero k=156..159 pad */                    \
    bf16x8 af_[5];                                                            \
    _Pragma("unroll")                                                         \
    for (int kf = 0; kf < 5; ++kf) af_[kf] = cv8(q0_[kf], q1_[kf]);           \
    asm volatile("s_waitcnt lgkmcnt(0)" ::: "memory");                        \
    __builtin_amdgcn_sched_barrier(0);                                        \
    if (ISS_) DMA_STEP(S_, TN_);   /* reuse just-consumed slot */             \
    f32x4 acc[8];                                                             \
    _Pragma("unroll")                                                         \
    for (int nt = 0; nt < 8; ++nt)                                            \
        acc[nt] = (f32x4){bias_v[nt], bias_v[nt], bias_v[nt], bias_v[nt]};    \
    _Pragma("unroll")                                                         \
    for (int kf = 0; kf < 5; ++kf)                                            \
        _Pragma("unroll")                                                     \
        for (int nt = 0; nt < 8; ++nt)                                        \
            acc[nt] = __builtin_amdgcn_mfma_f32_16x16x32_bf16(af_[kf], bfr[nt][kf], acc[nt], 0, 0, 0); \
    _Pragma("unroll")                                                         \
    for (int nt = 0; nt < 8; ++nt)                                            \
        acc[nt] = __builtin_amdgcn_mfma_f32_16x16x32_bf16(hf_, wrec[nt], acc[nt], 0, 0, 0); \
    _Pragma("unroll")                                                         \
    for (int ds = 0; ds < 2; ++ds)                                            \
        _Pragma("unroll")                                                     \
        for (int i = 0; i < 4; ++i) {                                         \
            float si = sigm(acc[0 + ds][i]);                                  \
            float sf = sigm(acc[2 + ds][i]);                                  \
            float tg = tanh_(acc[4 + ds][i]);                                 \
            float so = sigm(acc[6 + ds][i]);                                  \
            float c  = sf * cst[ds*4 + i] + si * tg;                          \
            float h  = so * tanh_(c);                                         \
            int cidx = ((lm>>3) + 2*ds)*128 + (lg*4 + i)*8 + (lm&7);          \
            if ((T_) == 3) {              /* end recent: stash h_r, reset */  \
                hcatf[w*1024 + cidx] = f2bf(h);                               \
                hfrag[w*512 + cidx]  = 0;                                     \
                cst[ds*4 + i] = 0.f;                                          \
            } else {                                                          \
                cst[ds*4 + i] = c;                                            \
                hfrag[w*512 + cidx] = f2bf(h);                                \
                if ((T_) == TT-1) hcatf[w*1024 + 512 + cidx] = f2bf(h);       \
            }                                                                 \
        }                                                                     \
    if ((T_) == 3) LOAD_FRAGS(Mbf + G4*160, Whhbf + G4*HLSTM, bias2 + G4);    \
    } while (0)

    // prologue: fill 3 slots (30 DMAs outstanding)
    DMA_STEP(0, 0);
    DMA_STEP(1, 1);
    DMA_STEP(2, 2);

    int s = 0;
    #pragma unroll 3
    for (int t = 0; t < TT-2; ++t) {          // t = 0..21
        WAITVM(20);                            // slot-t's 10 DMAs retired
        STEP(s, t, (t < TT-3), t+3);
        s = (s == 2) ? 0 : s + 1;
    }
    WAITVM(10);
    STEP(1, TT-2, 0, 0);                       // t = 22 (slot 22%3 = 1)
    WAITVM(0);
    STEP(2, TT-1, 0, 0);                       // t = 23 (slot 2)

    // ---- fc epilogue: out = [hr|hp] @ fcW^T + fcb (MFMA, K=64) ----
    {
        bf16x8 ha0 = *(const bf16x8*)(hcatf + w*1024 + l*8);
        bf16x8 ha1 = *(const bf16x8*)(hcatf + w*1024 + 512 + l*8);
        #pragma unroll
        for (int nt = 0; nt < 10; ++nt) {
            int n  = nt*16 + lm;
            int nc = n < 155 ? n : 155;
            const float* wp0 = fcW + nc*64 + lg*8;
            const float* wp1 = fcW + nc*64 + 32 + lg*8;
            bf16x8 wf0 = cv8(*(const float4*)wp0, *(const float4*)(wp0 + 4));
            bf16x8 wf1 = cv8(*(const float4*)wp1, *(const float4*)(wp1 + 4));
            f32x4 fa = (f32x4){0.f, 0.f, 0.f, 0.f};
            fa = __builtin_amdgcn_mfma_f32_16x16x32_bf16(ha0, wf0, fa, 0, 0, 0);
            fa = __builtin_amdgcn_mfma_f32_16x16x32_bf16(ha1, wf1, fa, 0, 0, 0);
            if (n < N_NODES) {
                float bn = fcb[n];
                #pragma unroll
                for (int i = 0; i < 4; ++i)
                    out[(size_t)(b0 + 16*w + lg*4 + i)*N_NODES + n] = fa[i] + bn;
            }
        }
    }
#undef STEP
#undef WAITVM
#undef DMA_STEP
#undef LOAD_FRAGS
}

extern "C" void kernel_launch(void* const* d_in, const int* in_sizes, int n_in,
                              void* d_out, int out_size, void* d_ws, size_t ws_size,
                              hipStream_t stream) {
    (void)in_sizes; (void)n_in; (void)out_size; (void)ws_size;
    const float* emb   = (const float*)d_in[0];
    const float* x     = (const float*)d_in[1];
    const int*   adj   = (const int*)d_in[2];
    const float* Wr    = (const float*)d_in[3];
    const float* ar    = (const float*)d_in[4];
    const float* Wp    = (const float*)d_in[5];
    const float* ap    = (const float*)d_in[6];
    const float* Wih_r = (const float*)d_in[7];
    const float* Whh_r = (const float*)d_in[8];
    const float* bih_r = (const float*)d_in[9];
    const float* bhh_r = (const float*)d_in[10];
    const float* Wih_p = (const float*)d_in[11];
    const float* Whh_p = (const float*)d_in[12];
    const float* bih_p = (const float*)d_in[13];
    const float* bhh_p = (const float*)d_in[14];
    const float* fcW   = (const float*)d_in[15];
    const float* fcb   = (const float*)d_in[16];
    float* out = (float*)d_out;

    char* ws = (char*)d_ws;
    size_t off = 0;
    auto alloc = [&](size_t bytes) {
        char* p = ws + off;
        off += (bytes + 255) & ~(size_t)255;
        return p;
    };
    float*          attn  = (float*)alloc(2*156*156*sizeof(float));
    float*          sbuf  = (float*)alloc(4*156*sizeof(float));
    unsigned short* Mbf   = (unsigned short*)alloc(2*G4*160*sizeof(unsigned short));
    unsigned short* Whhbf = (unsigned short*)alloc(2*G4*HLSTM*sizeof(unsigned short));
    float*          bias2 = (float*)alloc(2*G4*sizeof(float));

    k_gat_s<<<dim3(156, 2), 128, 0, stream>>>(emb, Wr, ar, Wp, ap, sbuf);
    k_attn<<<dim3(156, 2), 256, 0, stream>>>(sbuf, adj, attn);
    k_prep<<<dim3(128, 2), 192, 0, stream>>>(attn, Wih_r, Wih_p, Whh_r, Whh_p,
                                             bih_r, bhh_r, bih_p, bhh_p,
                                             Mbf, Whhbf, bias2);
    k_fused<<<dim3(BATCH/ROWS_B), NW*64, 0, stream>>>(x, Mbf, Whhbf, bias2, fcW, fcb, out);
}